// Round 1
// baseline (1345.439 us; speedup 1.0000x reference)
//
#include <hip/hip_runtime.h>

#define NN 50000
#define NE 800000

// ---------------- CSR build ----------------

__global__ void k_deg(const int* __restrict__ dst, int* __restrict__ deg, int e) {
    int i = blockIdx.x * blockDim.x + threadIdx.x;
    if (i < e) atomicAdd(&deg[dst[i]], 1);
}

__global__ __launch_bounds__(1024) void k_scan(const int* __restrict__ deg,
                                               int* __restrict__ row_start,
                                               int* __restrict__ cursor,
                                               float* __restrict__ inv_deg, int n) {
    __shared__ int part[1024];
    int tid = threadIdx.x;
    int ch = (n + 1023) >> 10;
    int lo = tid * ch;
    int hi = lo + ch; if (hi > n) hi = n;
    int local = 0;
    for (int i = lo; i < hi; ++i) local += deg[i];
    part[tid] = local;
    __syncthreads();
    for (int off = 1; off < 1024; off <<= 1) {
        int v = (tid >= off) ? part[tid - off] : 0;
        __syncthreads();
        part[tid] += v;
        __syncthreads();
    }
    int run = part[tid] - local;  // exclusive prefix
    for (int i = lo; i < hi; ++i) {
        int d = deg[i];
        row_start[i] = run;
        cursor[i] = run;
        inv_deg[i] = 1.0f / (float)(d > 1 ? d : 1);
        run += d;
    }
    if (tid == 1023) row_start[n] = part[1023];
}

__global__ void k_fill(const int* __restrict__ src, const int* __restrict__ dst,
                       int* __restrict__ cursor, int* __restrict__ col, int e) {
    int i = blockIdx.x * blockDim.x + threadIdx.x;
    if (i < e) {
        int pos = atomicAdd(&cursor[dst[i]], 1);
        col[pos] = src[i];
    }
}

// ---------------- mean aggregation (CSR gather), one wave per node ----------------

template <int D>
__global__ void k_agg(const float* __restrict__ h, const int* __restrict__ row_start,
                      const int* __restrict__ col, const float* __restrict__ inv_deg,
                      float* __restrict__ out, int n) {
    int wid = (blockIdx.x * blockDim.x + threadIdx.x) >> 6;  // node id
    int lane = threadIdx.x & 63;
    if (wid >= n) return;
    int s = row_start[wid];
    int e = row_start[wid + 1];
    float acc[D / 64];
#pragma unroll
    for (int j = 0; j < D / 64; ++j) acc[j] = 0.0f;
    for (int p = s; p < e; ++p) {
        int srcn = col[p];
#pragma unroll
        for (int j = 0; j < D / 64; ++j) acc[j] += h[srcn * D + j * 64 + lane];
    }
    float sc = inv_deg[wid];
#pragma unroll
    for (int j = 0; j < D / 64; ++j) out[wid * D + j * 64 + lane] = acc[j] * sc;
}

// ---------------- fused SAGE hidden layer: GEMM x2 + bias + LN + ReLU ----------------
// block = 128 threads (= OUT features), T=8 nodes per block

template <int K>
__global__ __launch_bounds__(128) void k_sage_hidden(
    const float* __restrict__ agg, const float* __restrict__ h,
    const float* __restrict__ Wl, const float* __restrict__ bl,
    const float* __restrict__ Wr, const float* __restrict__ g,
    const float* __restrict__ b, float* __restrict__ out, int n) {
    constexpr int T = 8;
    constexpr int OUT = 128;
    __shared__ float agg_s[T][K];
    __shared__ float h_s[T][K];
    __shared__ float o_s[T][OUT];
    int t = threadIdx.x;
    int n0 = blockIdx.x * T;
    for (int i = t; i < T * K; i += 128) {
        int nn = i / K, kk = i % K;
        int node = n0 + nn;
        agg_s[nn][kk] = (node < n) ? agg[node * K + kk] : 0.0f;
        h_s[nn][kk] = (node < n) ? h[node * K + kk] : 0.0f;
    }
    __syncthreads();
    float bias = bl[t];
    float acc[T];
#pragma unroll
    for (int i = 0; i < T; ++i) acc[i] = bias;
    for (int k = 0; k < K; ++k) {
        float wl = Wl[t * K + k];
        float wr = Wr[t * K + k];
#pragma unroll
        for (int i = 0; i < T; ++i) acc[i] += agg_s[i][k] * wl + h_s[i][k] * wr;
    }
#pragma unroll
    for (int i = 0; i < T; ++i) o_s[i][t] = acc[i];
    __syncthreads();
    // LayerNorm + ReLU: wave per node (2 waves, 4 nodes each)
    int wave = t >> 6, lane = t & 63;
    for (int nn = wave; nn < T; nn += 2) {
        float v0 = o_s[nn][lane];
        float v1 = o_s[nn][64 + lane];
        float sum = v0 + v1;
        float sq = v0 * v0 + v1 * v1;
#pragma unroll
        for (int off = 32; off > 0; off >>= 1) {
            sum += __shfl_xor(sum, off);
            sq += __shfl_xor(sq, off);
        }
        float mean = sum * (1.0f / 128.0f);
        float var = sq * (1.0f / 128.0f) - mean * mean;
        float r = rsqrtf(var + 1e-5f);
        int node = n0 + nn;
        if (node < n) {
            float y0 = fmaxf((v0 - mean) * r * g[lane] + b[lane], 0.0f);
            float y1 = fmaxf((v1 - mean) * r * g[64 + lane] + b[64 + lane], 0.0f);
            out[node * 128 + lane] = y0;
            out[node * 128 + 64 + lane] = y1;
        }
    }
}

// ---------------- final SAGE layer: GEMM x2 + bias, OUT=64, no LN ----------------

__global__ __launch_bounds__(64) void k_sage_final(
    const float* __restrict__ agg, const float* __restrict__ h,
    const float* __restrict__ Wl, const float* __restrict__ bl,
    const float* __restrict__ Wr, float* __restrict__ out, int n) {
    constexpr int T = 8;
    constexpr int K = 128;
    __shared__ float agg_s[T][K];
    __shared__ float h_s[T][K];
    int t = threadIdx.x;  // 0..63
    int n0 = blockIdx.x * T;
    for (int i = t; i < T * K; i += 64) {
        int nn = i / K, kk = i % K;
        int node = n0 + nn;
        agg_s[nn][kk] = (node < n) ? agg[node * K + kk] : 0.0f;
        h_s[nn][kk] = (node < n) ? h[node * K + kk] : 0.0f;
    }
    __syncthreads();
    float bias = bl[t];
    float acc[T];
#pragma unroll
    for (int i = 0; i < T; ++i) acc[i] = bias;
    for (int k = 0; k < K; ++k) {
        float wl = Wl[t * K + k];
        float wr = Wr[t * K + k];
#pragma unroll
        for (int i = 0; i < T; ++i) acc[i] += agg_s[i][k] * wl + h_s[i][k] * wr;
    }
#pragma unroll
    for (int i = 0; i < T; ++i) {
        int node = n0 + i;
        if (node < n) out[node * 64 + t] = acc[i];
    }
}

// ---------------- launch ----------------

extern "C" void kernel_launch(void* const* d_in, const int* in_sizes, int n_in,
                              void* d_out, int out_size, void* d_ws, size_t ws_size,
                              hipStream_t stream) {
    const float* x = (const float*)d_in[0];
    const int* ei = (const int*)d_in[1];
    const int* esrc = ei;
    const int* edst = ei + NE;

    const float* mWl0 = (const float*)d_in[2];
    const float* mbl0 = (const float*)d_in[3];
    const float* mWr0 = (const float*)d_in[4];
    const float* mg0  = (const float*)d_in[5];
    const float* mb0  = (const float*)d_in[6];
    const float* mWl1 = (const float*)d_in[7];
    const float* mbl1 = (const float*)d_in[8];
    const float* mWr1 = (const float*)d_in[9];
    const float* mg1  = (const float*)d_in[10];
    const float* mb1  = (const float*)d_in[11];
    const float* mWl2 = (const float*)d_in[12];
    const float* mbl2 = (const float*)d_in[13];
    const float* mWr2 = (const float*)d_in[14];
    const float* vWl0 = (const float*)d_in[15];
    const float* vbl0 = (const float*)d_in[16];
    const float* vWr0 = (const float*)d_in[17];
    const float* vg0  = (const float*)d_in[18];
    const float* vb0  = (const float*)d_in[19];
    const float* vWl1 = (const float*)d_in[20];
    const float* vbl1 = (const float*)d_in[21];
    const float* vWr1 = (const float*)d_in[22];
    const float* vg1  = (const float*)d_in[23];
    const float* vb1  = (const float*)d_in[24];
    const float* vWl2 = (const float*)d_in[25];
    const float* vbl2 = (const float*)d_in[26];
    const float* vWr2 = (const float*)d_in[27];

    // workspace bump allocator (256B aligned)
    char* p = (char*)d_ws;
    auto alloc = [&](size_t bytes) {
        void* r = (void*)p;
        p += (bytes + 255) & ~(size_t)255;
        return r;
    };
    int* deg       = (int*)alloc((size_t)NN * 4);
    int* row_start = (int*)alloc((size_t)(NN + 1) * 4);
    int* cursor    = (int*)alloc((size_t)NN * 4);
    int* col       = (int*)alloc((size_t)NE * 4);
    float* inv_deg = (float*)alloc((size_t)NN * 4);
    float* agg0    = (float*)alloc((size_t)NN * 64 * 4);
    float* h1      = (float*)alloc((size_t)NN * 128 * 4);
    float* aggb    = (float*)alloc((size_t)NN * 128 * 4);
    float* h2      = (float*)alloc((size_t)NN * 128 * 4);

    float* out_mu = (float*)d_out;
    float* out_lv = (float*)d_out + (size_t)NN * 64;

    // CSR build
    hipMemsetAsync(deg, 0, (size_t)NN * 4, stream);
    k_deg<<<(NE + 255) / 256, 256, 0, stream>>>(edst, deg, NE);
    k_scan<<<1, 1024, 0, stream>>>(deg, row_start, cursor, inv_deg, NN);
    k_fill<<<(NE + 255) / 256, 256, 0, stream>>>(esrc, edst, cursor, col, NE);

    // shared layer-0 aggregation of x
    k_agg<64><<<(NN + 3) / 4, 256, 0, stream>>>(x, row_start, col, inv_deg, agg0, NN);

    const int gh = (NN + 7) / 8;

    // mu tower
    k_sage_hidden<64><<<gh, 128, 0, stream>>>(agg0, x, mWl0, mbl0, mWr0, mg0, mb0, h1, NN);
    k_agg<128><<<(NN + 3) / 4, 256, 0, stream>>>(h1, row_start, col, inv_deg, aggb, NN);
    k_sage_hidden<128><<<gh, 128, 0, stream>>>(aggb, h1, mWl1, mbl1, mWr1, mg1, mb1, h2, NN);
    k_agg<128><<<(NN + 3) / 4, 256, 0, stream>>>(h2, row_start, col, inv_deg, aggb, NN);
    k_sage_final<<<gh, 64, 0, stream>>>(aggb, h2, mWl2, mbl2, mWr2, out_mu, NN);

    // logvar tower
    k_sage_hidden<64><<<gh, 128, 0, stream>>>(agg0, x, vWl0, vbl0, vWr0, vg0, vb0, h1, NN);
    k_agg<128><<<(NN + 3) / 4, 256, 0, stream>>>(h1, row_start, col, inv_deg, aggb, NN);
    k_sage_hidden<128><<<gh, 128, 0, stream>>>(aggb, h1, vWl1, vbl1, vWr1, vg1, vb1, h2, NN);
    k_agg<128><<<(NN + 3) / 4, 256, 0, stream>>>(h2, row_start, col, inv_deg, aggb, NN);
    k_sage_final<<<gh, 64, 0, stream>>>(aggb, h2, vWl2, vbl2, vWr2, out_lv, NN);
}

// Round 2
// 644.724 us; speedup vs baseline: 2.0868x; 2.0868x over previous
//
#include <hip/hip_runtime.h>

#define NN 50000
#define NE 800000
#define MPAD 50048   // 782 * 64

typedef __attribute__((ext_vector_type(8))) short short8;
typedef __attribute__((ext_vector_type(4))) float f32x4;

__device__ __forceinline__ ushort f2b(float f) {
    uint u = __builtin_bit_cast(uint, f);
    uint r = (u + 0x7fffu + ((u >> 16) & 1u)) >> 16;
    return (ushort)r;
}
__device__ __forceinline__ float blo(uint u) { return __builtin_bit_cast(float, u << 16); }
__device__ __forceinline__ float bhi(uint u) { return __builtin_bit_cast(float, u & 0xffff0000u); }

// ---------------- CSR build ----------------

__global__ void k_deg(const int* __restrict__ dst, int* __restrict__ deg, int e) {
    int i = blockIdx.x * blockDim.x + threadIdx.x;
    if (i < e) atomicAdd(&deg[dst[i]], 1);
}

__global__ __launch_bounds__(1024) void k_scan(const int* __restrict__ deg,
                                               int* __restrict__ row_start,
                                               int* __restrict__ cursor,
                                               float* __restrict__ inv_deg, int n) {
    __shared__ int part[1024];
    int tid = threadIdx.x;
    int ch = (n + 1023) >> 10;
    int lo = tid * ch;
    int hi = lo + ch; if (hi > n) hi = n;
    int local = 0;
    for (int i = lo; i < hi; ++i) local += deg[i];
    part[tid] = local;
    __syncthreads();
    for (int off = 1; off < 1024; off <<= 1) {
        int v = (tid >= off) ? part[tid - off] : 0;
        __syncthreads();
        part[tid] += v;
        __syncthreads();
    }
    int run = part[tid] - local;  // exclusive prefix
    for (int i = lo; i < hi; ++i) {
        int d = deg[i];
        row_start[i] = run;
        cursor[i] = run;
        inv_deg[i] = 1.0f / (float)(d > 1 ? d : 1);
        run += d;
    }
    if (tid == 1023) row_start[n] = part[1023];
}

__global__ void k_fill(const int* __restrict__ src, const int* __restrict__ dst,
                       int* __restrict__ cursor, int* __restrict__ col, int e) {
    int i = blockIdx.x * blockDim.x + threadIdx.x;
    if (i < e) {
        int pos = atomicAdd(&cursor[dst[i]], 1);
        col[pos] = src[i];
    }
}

// ---------------- conversions ----------------

__global__ void k_xcvt(const float* __restrict__ x, ushort* __restrict__ xb, int n2) {
    int i = blockIdx.x * blockDim.x + threadIdx.x;
    if (i < n2) {
        float2 v = *(const float2*)(x + (size_t)i * 2);
        uint pk = (uint)f2b(v.x) | ((uint)f2b(v.y) << 16);
        *(uint*)(xb + (size_t)i * 2) = pk;
    }
}

struct WArgs {
    const float* wl[6];
    const float* wr[6];
    ushort* wc[6];
};

// build Wcat[n][0..2KH) = [Wl[n][:] | Wr[n][:]] in bf16, for 6 layers
__global__ void k_wcvt(WArgs a) {
    const int khs[6] = {64, 128, 128, 64, 128, 128};
    const int shs[6] = {7, 8, 8, 7, 8, 8};  // log2(2*KH)
    const int off[6] = {0, 16384, 49152, 65536, 81920, 114688};
    int idx = blockIdx.x * blockDim.x + threadIdx.x;
    if (idx >= 131072) return;
    int L = 0;
#pragma unroll
    for (int i = 1; i < 6; ++i) if (idx >= off[i]) L = i;
    int j = idx - off[L];
    int KH = khs[L];
    int n = j >> shs[L];
    int kk = j & ((1 << shs[L]) - 1);
    float v = (kk < KH) ? a.wl[L][n * KH + kk] : a.wr[L][n * KH + kk - KH];
    a.wc[L][j] = f2b(v);
}

// ---------------- mean aggregation (CSR gather, bf16 in/out) ----------------
// one wave per node; grid.y selects tower

template <int D>
__global__ __launch_bounds__(256) void k_agg_bf(
    const ushort* __restrict__ hm, const ushort* __restrict__ hv,
    const int* __restrict__ row_start, const int* __restrict__ col,
    const float* __restrict__ inv_deg,
    ushort* __restrict__ om, ushort* __restrict__ ov) {
    const ushort* h = blockIdx.y ? hv : hm;
    ushort* o = blockIdx.y ? ov : om;
    int node = blockIdx.x * 4 + (threadIdx.x >> 6);
    if (node >= NN) return;
    int lane = threadIdx.x & 63;
    int s = row_start[node], e = row_start[node + 1];
    float sc = inv_deg[node];
    if (D == 128) {
        float a0 = 0.f, a1 = 0.f;
        int p = s;
        for (; p + 3 < e; p += 4) {
            int c0 = col[p], c1 = col[p + 1], c2 = col[p + 2], c3 = col[p + 3];
            uint u0 = *(const uint*)(h + (size_t)c0 * 128 + lane * 2);
            uint u1 = *(const uint*)(h + (size_t)c1 * 128 + lane * 2);
            uint u2 = *(const uint*)(h + (size_t)c2 * 128 + lane * 2);
            uint u3 = *(const uint*)(h + (size_t)c3 * 128 + lane * 2);
            a0 += blo(u0) + blo(u1) + blo(u2) + blo(u3);
            a1 += bhi(u0) + bhi(u1) + bhi(u2) + bhi(u3);
        }
        for (; p < e; ++p) {
            uint u = *(const uint*)(h + (size_t)col[p] * 128 + lane * 2);
            a0 += blo(u); a1 += bhi(u);
        }
        uint pk = (uint)f2b(a0 * sc) | ((uint)f2b(a1 * sc) << 16);
        *(uint*)(o + (size_t)node * 128 + lane * 2) = pk;
    } else {
        float a0 = 0.f;
        int p = s;
        for (; p + 3 < e; p += 4) {
            int c0 = col[p], c1 = col[p + 1], c2 = col[p + 2], c3 = col[p + 3];
            float v0 = __builtin_bit_cast(float, (uint)h[(size_t)c0 * 64 + lane] << 16);
            float v1 = __builtin_bit_cast(float, (uint)h[(size_t)c1 * 64 + lane] << 16);
            float v2 = __builtin_bit_cast(float, (uint)h[(size_t)c2 * 64 + lane] << 16);
            float v3 = __builtin_bit_cast(float, (uint)h[(size_t)c3 * 64 + lane] << 16);
            a0 += v0 + v1 + v2 + v3;
        }
        for (; p < e; ++p)
            a0 += __builtin_bit_cast(float, (uint)h[(size_t)col[p] * 64 + lane] << 16);
        o[(size_t)node * 64 + lane] = f2b(a0 * sc);
    }
}

// ---------------- fused MFMA GEMM (+bias [+LN+ReLU]) ----------------
// C[M x NOUT] = [agg | h] (M x 2KH, bf16) * Wcat^T (bf16), per-wave 16 rows x NOUT
// block = 4 waves = 64 rows; grid.y selects tower

struct GArgs {
    const ushort *A1m, *A1v, *A2m, *A2v, *Wm, *Wv;
    const float *blm, *blv, *gm, *gv, *bbm, *bbv;
    void *outm, *outv;
};

template <int KH, int NOUT, bool DO_LN>
__global__ __launch_bounds__(256) void k_gemm(GArgs a) {
    constexpr int NT = NOUT / 16;
    constexpr int NK = (2 * KH) / 32;
    int tow = blockIdx.y;
    const ushort* A1 = tow ? a.A1v : a.A1m;
    const ushort* A2 = tow ? a.A2v : a.A2m;
    const ushort* W  = tow ? a.Wv  : a.Wm;
    const float* bl  = tow ? a.blv : a.blm;
    int lane = threadIdx.x & 63;
    int wid  = threadIdx.x >> 6;
    int m0 = blockIdx.x * 64 + wid * 16;
    int r15 = lane & 15;
    int kseg = lane >> 4;
    size_t arow = (size_t)(m0 + r15);

    f32x4 acc[NT];
#pragma unroll
    for (int nt = 0; nt < NT; ++nt) acc[nt] = (f32x4){0.f, 0.f, 0.f, 0.f};

#pragma unroll
    for (int ks = 0; ks < NK; ++ks) {
        int kc = ks * 32 + kseg * 8;
        const ushort* ap = (kc < KH) ? (A1 + arow * KH + kc)
                                     : (A2 + arow * KH + (kc - KH));
        short8 af = *(const short8*)ap;
#pragma unroll
        for (int nt = 0; nt < NT; ++nt) {
            short8 bfr = *(const short8*)(W + (size_t)(nt * 16 + r15) * (2 * KH) + kc);
            acc[nt] = __builtin_amdgcn_mfma_f32_16x16x32_bf16(af, bfr, acc[nt], 0, 0, 0);
        }
    }

    // bias (before LN, like reference)
#pragma unroll
    for (int nt = 0; nt < NT; ++nt) {
        float bb = bl[nt * 16 + r15];
#pragma unroll
        for (int r = 0; r < 4; ++r) acc[nt][r] += bb;
    }

    if (DO_LN) {
        const float* g = tow ? a.gv : a.gm;
        const float* b = tow ? a.bbv : a.bbm;
        float s[4] = {0, 0, 0, 0}, q[4] = {0, 0, 0, 0};
#pragma unroll
        for (int nt = 0; nt < NT; ++nt)
#pragma unroll
            for (int r = 0; r < 4; ++r) { float v = acc[nt][r]; s[r] += v; q[r] += v * v; }
#pragma unroll
        for (int off = 1; off < 16; off <<= 1)
#pragma unroll
            for (int r = 0; r < 4; ++r) { s[r] += __shfl_xor(s[r], off); q[r] += __shfl_xor(q[r], off); }
        float mean[4], rstd[4];
#pragma unroll
        for (int r = 0; r < 4; ++r) {
            mean[r] = s[r] * (1.0f / NOUT);
            float var = q[r] * (1.0f / NOUT) - mean[r] * mean[r];
            rstd[r] = rsqrtf(var + 1e-5f);
        }
        ushort* out = (ushort*)(tow ? a.outv : a.outm);
#pragma unroll
        for (int nt = 0; nt < NT; ++nt) {
            int n = nt * 16 + r15;
            float gg = g[n], bb = b[n];
#pragma unroll
            for (int r = 0; r < 4; ++r) {
                int row = m0 + kseg * 4 + r;
                if (row < NN) {
                    float y = fmaxf((acc[nt][r] - mean[r]) * rstd[r] * gg + bb, 0.0f);
                    out[(size_t)row * NOUT + n] = f2b(y);
                }
            }
        }
    } else {
        float* out = (float*)(tow ? a.outv : a.outm);
#pragma unroll
        for (int nt = 0; nt < NT; ++nt) {
            int n = nt * 16 + r15;
#pragma unroll
            for (int r = 0; r < 4; ++r) {
                int row = m0 + kseg * 4 + r;
                if (row < NN) out[(size_t)row * NOUT + n] = acc[nt][r];
            }
        }
    }
}

// ---------------- launch ----------------

extern "C" void kernel_launch(void* const* d_in, const int* in_sizes, int n_in,
                              void* d_out, int out_size, void* d_ws, size_t ws_size,
                              hipStream_t stream) {
    const float* x = (const float*)d_in[0];
    const int* ei = (const int*)d_in[1];
    const int* esrc = ei;
    const int* edst = ei + NE;

    const float* mWl0 = (const float*)d_in[2];
    const float* mbl0 = (const float*)d_in[3];
    const float* mWr0 = (const float*)d_in[4];
    const float* mg0  = (const float*)d_in[5];
    const float* mb0  = (const float*)d_in[6];
    const float* mWl1 = (const float*)d_in[7];
    const float* mbl1 = (const float*)d_in[8];
    const float* mWr1 = (const float*)d_in[9];
    const float* mg1  = (const float*)d_in[10];
    const float* mb1  = (const float*)d_in[11];
    const float* mWl2 = (const float*)d_in[12];
    const float* mbl2 = (const float*)d_in[13];
    const float* mWr2 = (const float*)d_in[14];
    const float* vWl0 = (const float*)d_in[15];
    const float* vbl0 = (const float*)d_in[16];
    const float* vWr0 = (const float*)d_in[17];
    const float* vg0  = (const float*)d_in[18];
    const float* vb0  = (const float*)d_in[19];
    const float* vWl1 = (const float*)d_in[20];
    const float* vbl1 = (const float*)d_in[21];
    const float* vWr1 = (const float*)d_in[22];
    const float* vg1  = (const float*)d_in[23];
    const float* vb1  = (const float*)d_in[24];
    const float* vWl2 = (const float*)d_in[25];
    const float* vbl2 = (const float*)d_in[26];
    const float* vWr2 = (const float*)d_in[27];

    char* p = (char*)d_ws;
    auto alloc = [&](size_t bytes) {
        void* r = (void*)p;
        p += (bytes + 255) & ~(size_t)255;
        return r;
    };
    int* deg       = (int*)alloc((size_t)NN * 4);
    int* row_start = (int*)alloc((size_t)(NN + 1) * 4);
    int* cursor    = (int*)alloc((size_t)NN * 4);
    int* col       = (int*)alloc((size_t)NE * 4);
    float* inv_deg = (float*)alloc((size_t)NN * 4);
    ushort* x_bf   = (ushort*)alloc((size_t)MPAD * 64 * 2);
    ushort* agg0   = (ushort*)alloc((size_t)MPAD * 64 * 2);
    ushort* h1m    = (ushort*)alloc((size_t)MPAD * 128 * 2);
    ushort* h1v    = (ushort*)alloc((size_t)MPAD * 128 * 2);
    ushort* h2m    = (ushort*)alloc((size_t)MPAD * 128 * 2);
    ushort* h2v    = (ushort*)alloc((size_t)MPAD * 128 * 2);
    ushort* aggm   = (ushort*)alloc((size_t)MPAD * 128 * 2);
    ushort* aggv   = (ushort*)alloc((size_t)MPAD * 128 * 2);
    ushort* wc0    = (ushort*)alloc((size_t)128 * 128 * 2);
    ushort* wc1    = (ushort*)alloc((size_t)128 * 256 * 2);
    ushort* wc2    = (ushort*)alloc((size_t)64 * 256 * 2);
    ushort* wc3    = (ushort*)alloc((size_t)128 * 128 * 2);
    ushort* wc4    = (ushort*)alloc((size_t)128 * 256 * 2);
    ushort* wc5    = (ushort*)alloc((size_t)64 * 256 * 2);

    float* out_mu = (float*)d_out;
    float* out_lv = (float*)d_out + (size_t)NN * 64;

    // CSR build
    hipMemsetAsync(deg, 0, (size_t)NN * 4, stream);
    k_deg<<<(NE + 255) / 256, 256, 0, stream>>>(edst, deg, NE);
    k_scan<<<1, 1024, 0, stream>>>(deg, row_start, cursor, inv_deg, NN);
    k_fill<<<(NE + 255) / 256, 256, 0, stream>>>(esrc, edst, cursor, col, NE);

    // conversions
    k_xcvt<<<(NN * 64 / 2 + 255) / 256, 256, 0, stream>>>(x, x_bf, NN * 64 / 2);
    WArgs wa;
    wa.wl[0] = mWl0; wa.wr[0] = mWr0; wa.wc[0] = wc0;
    wa.wl[1] = mWl1; wa.wr[1] = mWr1; wa.wc[1] = wc1;
    wa.wl[2] = mWl2; wa.wr[2] = mWr2; wa.wc[2] = wc2;
    wa.wl[3] = vWl0; wa.wr[3] = vWr0; wa.wc[3] = wc3;
    wa.wl[4] = vWl1; wa.wr[4] = vWr1; wa.wc[4] = wc4;
    wa.wl[5] = vWl2; wa.wr[5] = vWr2; wa.wc[5] = wc5;
    k_wcvt<<<512, 256, 0, stream>>>(wa);

    const dim3 gAgg1(12500, 1), gAgg2(12500, 2);
    const dim3 gG(782, 2);

    // layer 0: shared agg of x
    k_agg_bf<64><<<gAgg1, 256, 0, stream>>>(x_bf, x_bf, row_start, col, inv_deg, agg0, agg0);
    {
        GArgs ga = {agg0, agg0, x_bf, x_bf, wc0, wc3,
                    mbl0, vbl0, mg0, vg0, mb0, vb0, h1m, h1v};
        k_gemm<64, 128, true><<<gG, 256, 0, stream>>>(ga);
    }
    // layer 1
    k_agg_bf<128><<<gAgg2, 256, 0, stream>>>(h1m, h1v, row_start, col, inv_deg, aggm, aggv);
    {
        GArgs ga = {aggm, aggv, h1m, h1v, wc1, wc4,
                    mbl1, vbl1, mg1, vg1, mb1, vb1, h2m, h2v};
        k_gemm<128, 128, true><<<gG, 256, 0, stream>>>(ga);
    }
    // layer 2 (final, fp32 out, no LN)
    k_agg_bf<128><<<gAgg2, 256, 0, stream>>>(h2m, h2v, row_start, col, inv_deg, aggm, aggv);
    {
        GArgs ga = {aggm, aggv, h2m, h2v, wc2, wc5,
                    mbl2, vbl2, nullptr, nullptr, nullptr, nullptr, out_mu, out_lv};
        k_gemm<128, 64, false><<<gG, 256, 0, stream>>>(ga);
    }
}

// Round 3
// 523.707 us; speedup vs baseline: 2.5691x; 1.2311x over previous
//
#include <hip/hip_runtime.h>

#define NN 50000
#define NE 800000
#define MPAD 50048   // 782 * 64
#define SCAN_BLK 512
#define SCAN_NB 98   // ceil(NN/512)

typedef __attribute__((ext_vector_type(8))) short short8;
typedef __attribute__((ext_vector_type(4))) float f32x4;

__device__ __forceinline__ ushort f2b(float f) {
    uint u = __builtin_bit_cast(uint, f);
    uint r = (u + 0x7fffu + ((u >> 16) & 1u)) >> 16;
    return (ushort)r;
}
__device__ __forceinline__ float blo(uint u) { return __builtin_bit_cast(float, u << 16); }
__device__ __forceinline__ float bhi(uint u) { return __builtin_bit_cast(float, u & 0xffff0000u); }

// ---------------- CSR build ----------------

__global__ void k_deg(const int* __restrict__ dst, int* __restrict__ deg, int e) {
    int i = blockIdx.x * blockDim.x + threadIdx.x;
    if (i < e) atomicAdd(&deg[dst[i]], 1);
}

// phase 1: per-block partial sums of deg
__global__ __launch_bounds__(SCAN_BLK) void k_part(const int* __restrict__ deg,
                                                   int* __restrict__ part) {
    __shared__ int s[SCAN_BLK];
    int i = blockIdx.x * SCAN_BLK + threadIdx.x;
    s[threadIdx.x] = (i < NN) ? deg[i] : 0;
    __syncthreads();
#pragma unroll
    for (int off = SCAN_BLK / 2; off > 0; off >>= 1) {
        if (threadIdx.x < off) s[threadIdx.x] += s[threadIdx.x + off];
        __syncthreads();
    }
    if (threadIdx.x == 0) part[blockIdx.x] = s[0];
}

// phase 2: exclusive scan of the 98 partials (single tiny block)
__global__ __launch_bounds__(128) void k_scan_small(int* __restrict__ part) {
    __shared__ int s[128];
    int tid = threadIdx.x;
    int v = (tid < SCAN_NB) ? part[tid] : 0;
    s[tid] = v;
    __syncthreads();
#pragma unroll
    for (int off = 1; off < 128; off <<= 1) {
        int t = (tid >= off) ? s[tid - off] : 0;
        __syncthreads();
        s[tid] += t;
        __syncthreads();
    }
    if (tid < SCAN_NB) part[tid] = s[tid] - v;
}

// phase 3: block-local scan + global offset -> row_start / cursor / inv_deg
__global__ __launch_bounds__(SCAN_BLK) void k_rows(const int* __restrict__ deg,
                                                   const int* __restrict__ part,
                                                   int* __restrict__ row_start,
                                                   int* __restrict__ cursor,
                                                   float* __restrict__ inv_deg) {
    __shared__ int s[SCAN_BLK];
    int i = blockIdx.x * SCAN_BLK + threadIdx.x;
    int d = (i < NN) ? deg[i] : 0;
    s[threadIdx.x] = d;
    __syncthreads();
#pragma unroll
    for (int off = 1; off < SCAN_BLK; off <<= 1) {
        int t = (threadIdx.x >= off) ? s[threadIdx.x - off] : 0;
        __syncthreads();
        s[threadIdx.x] += t;
        __syncthreads();
    }
    int excl = s[threadIdx.x] - d + part[blockIdx.x];
    if (i < NN) {
        row_start[i] = excl;
        cursor[i] = excl;
        inv_deg[i] = 1.0f / (float)(d > 1 ? d : 1);
        if (i == NN - 1) row_start[NN] = excl + d;
    }
}

__global__ void k_fill(const int* __restrict__ src, const int* __restrict__ dst,
                       int* __restrict__ cursor, int* __restrict__ col, int e) {
    int i = blockIdx.x * blockDim.x + threadIdx.x;
    if (i < e) {
        int pos = atomicAdd(&cursor[dst[i]], 1);
        col[pos] = src[i];
    }
}

// ---------------- conversions ----------------

__global__ void k_xcvt(const float* __restrict__ x, ushort* __restrict__ xb, int n2) {
    int i = blockIdx.x * blockDim.x + threadIdx.x;
    if (i < n2) {
        float2 v = *(const float2*)(x + (size_t)i * 2);
        uint pk = (uint)f2b(v.x) | ((uint)f2b(v.y) << 16);
        *(uint*)(xb + (size_t)i * 2) = pk;
    }
}

struct WArgs {
    const float* wl[6];
    const float* wr[6];
    ushort* wc[6];
};

// build Wcat[n][0..2KH) = [Wl[n][:] | Wr[n][:]] in bf16, for 6 layers
__global__ void k_wcvt(WArgs a) {
    const int khs[6] = {64, 128, 128, 64, 128, 128};
    const int shs[6] = {7, 8, 8, 7, 8, 8};  // log2(2*KH)
    const int off[6] = {0, 16384, 49152, 65536, 81920, 114688};
    int idx = blockIdx.x * blockDim.x + threadIdx.x;
    if (idx >= 131072) return;
    int L = 0;
#pragma unroll
    for (int i = 1; i < 6; ++i) if (idx >= off[i]) L = i;
    int j = idx - off[L];
    int KH = khs[L];
    int n = j >> shs[L];
    int kk = j & ((1 << shs[L]) - 1);
    float v = (kk < KH) ? a.wl[L][n * KH + kk] : a.wr[L][n * KH + kk - KH];
    a.wc[L][j] = f2b(v);
}

// ---------------- mean aggregation (CSR gather, bf16 in/out) ----------------
// one wave per node; grid.y selects tower

template <int D>
__global__ __launch_bounds__(256) void k_agg_bf(
    const ushort* __restrict__ hm, const ushort* __restrict__ hv,
    const int* __restrict__ row_start, const int* __restrict__ col,
    const float* __restrict__ inv_deg,
    ushort* __restrict__ om, ushort* __restrict__ ov) {
    const ushort* h = blockIdx.y ? hv : hm;
    ushort* o = blockIdx.y ? ov : om;
    int node = blockIdx.x * 4 + (threadIdx.x >> 6);
    if (node >= NN) return;
    int lane = threadIdx.x & 63;
    int s = row_start[node], e = row_start[node + 1];
    float sc = inv_deg[node];
    if (D == 128) {
        float a0 = 0.f, a1 = 0.f;
        int p = s;
        for (; p + 3 < e; p += 4) {
            int c0 = col[p], c1 = col[p + 1], c2 = col[p + 2], c3 = col[p + 3];
            uint u0 = *(const uint*)(h + (size_t)c0 * 128 + lane * 2);
            uint u1 = *(const uint*)(h + (size_t)c1 * 128 + lane * 2);
            uint u2 = *(const uint*)(h + (size_t)c2 * 128 + lane * 2);
            uint u3 = *(const uint*)(h + (size_t)c3 * 128 + lane * 2);
            a0 += blo(u0) + blo(u1) + blo(u2) + blo(u3);
            a1 += bhi(u0) + bhi(u1) + bhi(u2) + bhi(u3);
        }
        for (; p < e; ++p) {
            uint u = *(const uint*)(h + (size_t)col[p] * 128 + lane * 2);
            a0 += blo(u); a1 += bhi(u);
        }
        uint pk = (uint)f2b(a0 * sc) | ((uint)f2b(a1 * sc) << 16);
        *(uint*)(o + (size_t)node * 128 + lane * 2) = pk;
    } else {
        float a0 = 0.f;
        int p = s;
        for (; p + 3 < e; p += 4) {
            int c0 = col[p], c1 = col[p + 1], c2 = col[p + 2], c3 = col[p + 3];
            float v0 = __builtin_bit_cast(float, (uint)h[(size_t)c0 * 64 + lane] << 16);
            float v1 = __builtin_bit_cast(float, (uint)h[(size_t)c1 * 64 + lane] << 16);
            float v2 = __builtin_bit_cast(float, (uint)h[(size_t)c2 * 64 + lane] << 16);
            float v3 = __builtin_bit_cast(float, (uint)h[(size_t)c3 * 64 + lane] << 16);
            a0 += v0 + v1 + v2 + v3;
        }
        for (; p < e; ++p)
            a0 += __builtin_bit_cast(float, (uint)h[(size_t)col[p] * 64 + lane] << 16);
        o[(size_t)node * 64 + lane] = f2b(a0 * sc);
    }
}

// ---------------- fused MFMA GEMM (+bias [+LN+ReLU]) ----------------
// C[M x NOUT] = [agg | h] (M x 2KH, bf16) * Wcat^T (bf16), per-wave 16 rows x NOUT
// block = 4 waves = 64 rows; grid.y selects tower

struct GArgs {
    const ushort *A1m, *A1v, *A2m, *A2v, *Wm, *Wv;
    const float *blm, *blv, *gm, *gv, *bbm, *bbv;
    void *outm, *outv;
};

template <int KH, int NOUT, bool DO_LN>
__global__ __launch_bounds__(256) void k_gemm(GArgs a) {
    constexpr int NT = NOUT / 16;
    constexpr int NK = (2 * KH) / 32;
    int tow = blockIdx.y;
    const ushort* A1 = tow ? a.A1v : a.A1m;
    const ushort* A2 = tow ? a.A2v : a.A2m;
    const ushort* W  = tow ? a.Wv  : a.Wm;
    const float* bl  = tow ? a.blv : a.blm;
    int lane = threadIdx.x & 63;
    int wid  = threadIdx.x >> 6;
    int m0 = blockIdx.x * 64 + wid * 16;
    int r15 = lane & 15;
    int kseg = lane >> 4;
    size_t arow = (size_t)(m0 + r15);

    f32x4 acc[NT];
#pragma unroll
    for (int nt = 0; nt < NT; ++nt) acc[nt] = (f32x4){0.f, 0.f, 0.f, 0.f};

#pragma unroll
    for (int ks = 0; ks < NK; ++ks) {
        int kc = ks * 32 + kseg * 8;
        const ushort* ap = (kc < KH) ? (A1 + arow * KH + kc)
                                     : (A2 + arow * KH + (kc - KH));
        short8 af = *(const short8*)ap;
#pragma unroll
        for (int nt = 0; nt < NT; ++nt) {
            short8 bfr = *(const short8*)(W + (size_t)(nt * 16 + r15) * (2 * KH) + kc);
            acc[nt] = __builtin_amdgcn_mfma_f32_16x16x32_bf16(af, bfr, acc[nt], 0, 0, 0);
        }
    }

    // bias (before LN, like reference)
#pragma unroll
    for (int nt = 0; nt < NT; ++nt) {
        float bb = bl[nt * 16 + r15];
#pragma unroll
        for (int r = 0; r < 4; ++r) acc[nt][r] += bb;
    }

    if (DO_LN) {
        const float* g = tow ? a.gv : a.gm;
        const float* b = tow ? a.bbv : a.bbm;
        float s[4] = {0, 0, 0, 0}, q[4] = {0, 0, 0, 0};
#pragma unroll
        for (int nt = 0; nt < NT; ++nt)
#pragma unroll
            for (int r = 0; r < 4; ++r) { float v = acc[nt][r]; s[r] += v; q[r] += v * v; }
#pragma unroll
        for (int off = 1; off < 16; off <<= 1)
#pragma unroll
            for (int r = 0; r < 4; ++r) { s[r] += __shfl_xor(s[r], off); q[r] += __shfl_xor(q[r], off); }
        float mean[4], rstd[4];
#pragma unroll
        for (int r = 0; r < 4; ++r) {
            mean[r] = s[r] * (1.0f / NOUT);
            float var = q[r] * (1.0f / NOUT) - mean[r] * mean[r];
            rstd[r] = rsqrtf(var + 1e-5f);
        }
        ushort* out = (ushort*)(tow ? a.outv : a.outm);
#pragma unroll
        for (int nt = 0; nt < NT; ++nt) {
            int n = nt * 16 + r15;
            float gg = g[n], bb = b[n];
#pragma unroll
            for (int r = 0; r < 4; ++r) {
                int row = m0 + kseg * 4 + r;
                if (row < NN) {
                    float y = fmaxf((acc[nt][r] - mean[r]) * rstd[r] * gg + bb, 0.0f);
                    out[(size_t)row * NOUT + n] = f2b(y);
                }
            }
        }
    } else {
        float* out = (float*)(tow ? a.outv : a.outm);
#pragma unroll
        for (int nt = 0; nt < NT; ++nt) {
            int n = nt * 16 + r15;
#pragma unroll
            for (int r = 0; r < 4; ++r) {
                int row = m0 + kseg * 4 + r;
                if (row < NN) out[(size_t)row * NOUT + n] = acc[nt][r];
            }
        }
    }
}

// ---------------- launch ----------------

extern "C" void kernel_launch(void* const* d_in, const int* in_sizes, int n_in,
                              void* d_out, int out_size, void* d_ws, size_t ws_size,
                              hipStream_t stream) {
    const float* x = (const float*)d_in[0];
    const int* ei = (const int*)d_in[1];
    const int* esrc = ei;
    const int* edst = ei + NE;

    const float* mWl0 = (const float*)d_in[2];
    const float* mbl0 = (const float*)d_in[3];
    const float* mWr0 = (const float*)d_in[4];
    const float* mg0  = (const float*)d_in[5];
    const float* mb0  = (const float*)d_in[6];
    const float* mWl1 = (const float*)d_in[7];
    const float* mbl1 = (const float*)d_in[8];
    const float* mWr1 = (const float*)d_in[9];
    const float* mg1  = (const float*)d_in[10];
    const float* mb1  = (const float*)d_in[11];
    const float* mWl2 = (const float*)d_in[12];
    const float* mbl2 = (const float*)d_in[13];
    const float* mWr2 = (const float*)d_in[14];
    const float* vWl0 = (const float*)d_in[15];
    const float* vbl0 = (const float*)d_in[16];
    const float* vWr0 = (const float*)d_in[17];
    const float* vg0  = (const float*)d_in[18];
    const float* vb0  = (const float*)d_in[19];
    const float* vWl1 = (const float*)d_in[20];
    const float* vbl1 = (const float*)d_in[21];
    const float* vWr1 = (const float*)d_in[22];
    const float* vg1  = (const float*)d_in[23];
    const float* vb1  = (const float*)d_in[24];
    const float* vWl2 = (const float*)d_in[25];
    const float* vbl2 = (const float*)d_in[26];
    const float* vWr2 = (const float*)d_in[27];

    char* p = (char*)d_ws;
    auto alloc = [&](size_t bytes) {
        void* r = (void*)p;
        p += (bytes + 255) & ~(size_t)255;
        return r;
    };
    int* deg       = (int*)alloc((size_t)NN * 4);
    int* part      = (int*)alloc((size_t)SCAN_NB * 4);
    int* row_start = (int*)alloc((size_t)(NN + 1) * 4);
    int* cursor    = (int*)alloc((size_t)NN * 4);
    int* col       = (int*)alloc((size_t)NE * 4);
    float* inv_deg = (float*)alloc((size_t)NN * 4);
    ushort* x_bf   = (ushort*)alloc((size_t)MPAD * 64 * 2);
    ushort* agg0   = (ushort*)alloc((size_t)MPAD * 64 * 2);
    ushort* h1m    = (ushort*)alloc((size_t)MPAD * 128 * 2);
    ushort* h1v    = (ushort*)alloc((size_t)MPAD * 128 * 2);
    ushort* h2m    = (ushort*)alloc((size_t)MPAD * 128 * 2);
    ushort* h2v    = (ushort*)alloc((size_t)MPAD * 128 * 2);
    ushort* aggm   = (ushort*)alloc((size_t)MPAD * 128 * 2);
    ushort* aggv   = (ushort*)alloc((size_t)MPAD * 128 * 2);
    ushort* wc0    = (ushort*)alloc((size_t)128 * 128 * 2);
    ushort* wc1    = (ushort*)alloc((size_t)128 * 256 * 2);
    ushort* wc2    = (ushort*)alloc((size_t)64 * 256 * 2);
    ushort* wc3    = (ushort*)alloc((size_t)128 * 128 * 2);
    ushort* wc4    = (ushort*)alloc((size_t)128 * 256 * 2);
    ushort* wc5    = (ushort*)alloc((size_t)64 * 256 * 2);

    float* out_mu = (float*)d_out;
    float* out_lv = (float*)d_out + (size_t)NN * 64;

    // CSR build (3-phase parallel scan)
    hipMemsetAsync(deg, 0, (size_t)NN * 4, stream);
    k_deg<<<(NE + 255) / 256, 256, 0, stream>>>(edst, deg, NE);
    k_part<<<SCAN_NB, SCAN_BLK, 0, stream>>>(deg, part);
    k_scan_small<<<1, 128, 0, stream>>>(part);
    k_rows<<<SCAN_NB, SCAN_BLK, 0, stream>>>(deg, part, row_start, cursor, inv_deg);
    k_fill<<<(NE + 255) / 256, 256, 0, stream>>>(esrc, edst, cursor, col, NE);

    // conversions
    k_xcvt<<<(NN * 64 / 2 + 255) / 256, 256, 0, stream>>>(x, x_bf, NN * 64 / 2);
    WArgs wa;
    wa.wl[0] = mWl0; wa.wr[0] = mWr0; wa.wc[0] = wc0;
    wa.wl[1] = mWl1; wa.wr[1] = mWr1; wa.wc[1] = wc1;
    wa.wl[2] = mWl2; wa.wr[2] = mWr2; wa.wc[2] = wc2;
    wa.wl[3] = vWl0; wa.wr[3] = vWr0; wa.wc[3] = wc3;
    wa.wl[4] = vWl1; wa.wr[4] = vWr1; wa.wc[4] = wc4;
    wa.wl[5] = vWl2; wa.wr[5] = vWr2; wa.wc[5] = wc5;
    k_wcvt<<<512, 256, 0, stream>>>(wa);

    const dim3 gAgg1(12500, 1), gAgg2(12500, 2);
    const dim3 gG(782, 2);

    // layer 0: shared agg of x
    k_agg_bf<64><<<gAgg1, 256, 0, stream>>>(x_bf, x_bf, row_start, col, inv_deg, agg0, agg0);
    {
        GArgs ga = {agg0, agg0, x_bf, x_bf, wc0, wc3,
                    mbl0, vbl0, mg0, vg0, mb0, vb0, h1m, h1v};
        k_gemm<64, 128, true><<<gG, 256, 0, stream>>>(ga);
    }
    // layer 1
    k_agg_bf<128><<<gAgg2, 256, 0, stream>>>(h1m, h1v, row_start, col, inv_deg, aggm, aggv);
    {
        GArgs ga = {aggm, aggv, h1m, h1v, wc1, wc4,
                    mbl1, vbl1, mg1, vg1, mb1, vb1, h2m, h2v};
        k_gemm<128, 128, true><<<gG, 256, 0, stream>>>(ga);
    }
    // layer 2 (final, fp32 out, no LN)
    k_agg_bf<128><<<gAgg2, 256, 0, stream>>>(h2m, h2v, row_start, col, inv_deg, aggm, aggv);
    {
        GArgs ga = {aggm, aggv, h2m, h2v, wc2, wc5,
                    mbl2, vbl2, nullptr, nullptr, nullptr, nullptr, out_mu, out_lv};
        k_gemm<128, 64, false><<<gG, 256, 0, stream>>>(ga);
    }
}